// Round 1
// baseline (1656.135 us; speedup 1.0000x reference)
//
#include <hip/hip_runtime.h>

#define H 128
#define BM 128
#define BN 64
#define BK 64
#define APAD 132   // 128 + 4: keeps 16B alignment for b128 reads, breaks bank conflicts
#define BPAD 68    // 64 + 4

// ---------------- CSR build ----------------

__global__ void k_hist(const int* __restrict__ dst, int E, int* __restrict__ cnt) {
    int e = blockIdx.x * 256 + threadIdx.x;
    if (e < E) atomicAdd(&cnt[dst[e]], 1);
}

__global__ void k_scan1(const int* __restrict__ cnt, int N,
                        int* __restrict__ incl, int* __restrict__ bsum) {
    __shared__ int s[256];
    int i = blockIdx.x * 256 + threadIdx.x;
    int v = (i < N) ? cnt[i] : 0;
    s[threadIdx.x] = v;
    __syncthreads();
    for (int d = 1; d < 256; d <<= 1) {
        int t = (threadIdx.x >= d) ? s[threadIdx.x - d] : 0;
        __syncthreads();
        s[threadIdx.x] += t;
        __syncthreads();
    }
    if (i < N) incl[i] = s[threadIdx.x];
    if (threadIdx.x == 255) bsum[blockIdx.x] = s[255];
}

__global__ void k_scan2(const int* __restrict__ bsum, int nb, int* __restrict__ bsumx) {
    __shared__ int s[512];
    int t = threadIdx.x;
    int v = (t < nb) ? bsum[t] : 0;
    s[t] = v;
    __syncthreads();
    for (int d = 1; d < 512; d <<= 1) {
        int u = (t >= d) ? s[t - d] : 0;
        __syncthreads();
        s[t] += u;
        __syncthreads();
    }
    if (t < nb) bsumx[t] = s[t] - v;   // exclusive block prefix
}

__global__ void k_scan3(const int* __restrict__ incl, const int* __restrict__ bsumx,
                        int N, int* __restrict__ off, int* __restrict__ cursor) {
    int i = blockIdx.x * 256 + threadIdx.x;
    if (i < N) {
        int g = incl[i] + bsumx[i >> 8];
        off[i + 1] = g;
        cursor[i + 1] = g;
        if (i == 0) { off[0] = 0; cursor[0] = 0; }
    }
}

__global__ void k_fill(const int* __restrict__ dst, int E,
                       int* __restrict__ cursor, int* __restrict__ eid) {
    int e = blockIdx.x * 256 + threadIdx.x;
    if (e < E) {
        int d = dst[e];
        int p = atomicAdd(&cursor[d], 1);
        eid[p] = e;
    }
}

// ---------------- gather (one wave per node) ----------------

__global__ void k_gather(const float* __restrict__ x, const float* __restrict__ ea,
                         const int* __restrict__ src, const int* __restrict__ eid,
                         const int* __restrict__ off, const int* __restrict__ cnt,
                         int N, float* __restrict__ aggx, float* __restrict__ agge) {
    int lane = threadIdx.x & 63;
    int n = blockIdx.x * 4 + (threadIdx.x >> 6);
    if (n >= N) return;
    int b = off[n], e1 = off[n + 1];
    float axx = 0.f, axy = 0.f, aex = 0.f, aey = 0.f;
    for (int p = b; p < e1; ++p) {
        int id = eid[p];
        int s  = src[id];
        float2 xv = ((const float2*)(x  + (size_t)s  * H))[lane];
        float2 ev = ((const float2*)(ea + (size_t)id * H))[lane];
        axx += xv.x; axy += xv.y;
        aex += ev.x; aey += ev.y;
    }
    int c = cnt[n];
    float sc = 1.0f / (float)(c > 1 ? c : 1);
    float2 ox = { axx * sc, axy * sc };
    float2 oe = { aex * sc, aey * sc };
    ((float2*)(aggx + (size_t)n * H))[lane] = ox;
    ((float2*)(agge + (size_t)n * H))[lane] = oe;
}

// ---------------- weight pack: wcat[(m*128 + k)][j] = Wm[j][k] ----------------

__global__ void k_pack(const float* __restrict__ wself, const float* __restrict__ wnei,
                       const float* __restrict__ wedge, float* __restrict__ wcat) {
    int t = blockIdx.x * 256 + threadIdx.x;
    if (t >= 3 * 128 * 128) return;
    int m = t >> 14;
    int r = t & 16383;
    int k = r >> 7;
    int j = r & 127;
    const float* W = (m == 0) ? wself : (m == 1) ? wnei : wedge;
    wcat[(size_t)((m << 7) + k) * 128 + j] = W[j * 128 + k];
}

// ---------------- fused 3-GEMM + bias + relu ----------------
// out[i][j] = relu( sum_k x[i][k] Ws[j][k] + aggx[i][k] Wn[j][k] + agge[i][k] We[j][k] + b[j] )

__launch_bounds__(256)
__global__ void k_gemm(const float* __restrict__ x, const float* __restrict__ aggx,
                       const float* __restrict__ agge, const float* __restrict__ wcat,
                       const float* __restrict__ bias, int N, float* __restrict__ out) {
    __shared__ float At[BK][APAD];   // 33792 B
    __shared__ float Bt[BK][BPAD];   // 17408 B

    int bid = blockIdx.x;
    int rb = bid >> 1, cb = bid & 1;
    int row0 = rb * BM, col0 = cb * BN;
    int t = threadIdx.x;
    int tj = t & 15, ti = t >> 4;
    int j0 = tj * 4, i0 = ti * 8;

    float acc[8][4] = {};

    for (int kt = 0; kt < 6; ++kt) {
        const float* A = (kt < 2) ? x : (kt < 4) ? aggx : agge;
        int kcol = (kt & 1) * 64;

        // stage A (transposed): 128 rows x 64 k
        {
            int kq = t & 15, r0 = t >> 4;
            #pragma unroll
            for (int p = 0; p < 8; ++p) {
                int r = r0 + p * 16;
                int row = row0 + r;
                float4 v = {0.f, 0.f, 0.f, 0.f};
                if (row < N) v = *(const float4*)(A + (size_t)row * H + kcol + kq * 4);
                At[kq * 4 + 0][r] = v.x;
                At[kq * 4 + 1][r] = v.y;
                At[kq * 4 + 2][r] = v.z;
                At[kq * 4 + 3][r] = v.w;
            }
        }
        // stage B: 64 k x 64 j slice of wcat
        {
            #pragma unroll
            for (int p = 0; p < 4; ++p) {
                int kr = (t >> 4) + p * 16;
                float4 v = *(const float4*)(wcat + (size_t)(kt * 64 + kr) * 128 + col0 + (t & 15) * 4);
                *(float4*)&Bt[kr][(t & 15) * 4] = v;
            }
        }
        __syncthreads();

        #pragma unroll 8
        for (int k = 0; k < BK; ++k) {
            float4 a0 = *(const float4*)&At[k][i0];
            float4 a1 = *(const float4*)&At[k][i0 + 4];
            float4 b4 = *(const float4*)&Bt[k][j0];
            float av[8] = {a0.x, a0.y, a0.z, a0.w, a1.x, a1.y, a1.z, a1.w};
            float bw[4] = {b4.x, b4.y, b4.z, b4.w};
            #pragma unroll
            for (int r = 0; r < 8; ++r)
                #pragma unroll
                for (int c = 0; c < 4; ++c)
                    acc[r][c] = fmaf(av[r], bw[c], acc[r][c]);
        }
        __syncthreads();
    }

    float4 bv = *(const float4*)(bias + col0 + j0);
    #pragma unroll
    for (int r = 0; r < 8; ++r) {
        int row = row0 + i0 + r;
        if (row < N) {
            float4 o;
            o.x = fmaxf(acc[r][0] + bv.x, 0.f);
            o.y = fmaxf(acc[r][1] + bv.y, 0.f);
            o.z = fmaxf(acc[r][2] + bv.z, 0.f);
            o.w = fmaxf(acc[r][3] + bv.w, 0.f);
            *(float4*)(out + (size_t)row * H + col0 + j0) = o;
        }
    }
}

// ---------------- launch ----------------

extern "C" void kernel_launch(void* const* d_in, const int* in_sizes, int n_in,
                              void* d_out, int out_size, void* d_ws, size_t ws_size,
                              hipStream_t stream) {
    const float* x     = (const float*)d_in[0];
    const int*   ei    = (const int*)d_in[1];
    const float* eattr = (const float*)d_in[2];
    const float* wself = (const float*)d_in[3];
    const float* bias  = (const float*)d_in[4];
    const float* wnei  = (const float*)d_in[5];
    const float* wedge = (const float*)d_in[6];
    float* out = (float*)d_out;

    const int N = in_sizes[0] / H;
    const int E = in_sizes[1] / 2;
    const int* srcI = ei;         // edge_index[0]
    const int* dstI = ei + E;     // edge_index[1]

    char* ws = (char*)d_ws;
    size_t o = 0;
    auto alloc = [&](size_t bytes) -> char* {
        char* p = ws + o;
        o = (o + bytes + 255) & ~(size_t)255;
        return p;
    };
    float* aggx  = (float*)alloc((size_t)N * H * sizeof(float));
    float* agge  = (float*)alloc((size_t)N * H * sizeof(float));
    int* cnt     = (int*)alloc((size_t)N * 4);
    int* offp    = (int*)alloc(((size_t)N + 1) * 4);
    int* cursor  = (int*)alloc(((size_t)N + 1) * 4);
    int* incl    = (int*)alloc((size_t)N * 4);
    int* bsum    = (int*)alloc(512 * 4);
    int* bsumx   = (int*)alloc(512 * 4);
    int* eid     = (int*)alloc((size_t)E * 4);
    float* wcat  = (float*)alloc((size_t)3 * 128 * 128 * sizeof(float));

    hipMemsetAsync(cnt, 0, (size_t)N * 4, stream);

    int nbE = (E + 255) / 256;
    int nbN = (N + 255) / 256;

    k_hist<<<nbE, 256, 0, stream>>>(dstI, E, cnt);
    k_scan1<<<nbN, 256, 0, stream>>>(cnt, N, incl, bsum);
    k_scan2<<<1, 512, 0, stream>>>(bsum, nbN, bsumx);
    k_scan3<<<nbN, 256, 0, stream>>>(incl, bsumx, N, offp, cursor);
    k_fill<<<nbE, 256, 0, stream>>>(dstI, E, cursor, eid);
    k_gather<<<(N + 3) / 4, 256, 0, stream>>>(x, eattr, srcI, eid, offp, cnt, N, aggx, agge);
    k_pack<<<(3 * 128 * 128 + 255) / 256, 256, 0, stream>>>(wself, wnei, wedge, wcat);

    int rb = (N + BM - 1) / BM;
    k_gemm<<<rb * 2, 256, 0, stream>>>(x, aggx, agge, wcat, bias, N, out);
}